// Round 12
// baseline (43.781 us; speedup 1.0000x reference)
//
#include <hip/hip_runtime.h>
#include <math.h>

namespace {

constexpr int C      = 25;
constexpr int ROWS   = 256;          // rows per tile (= blockDim.x)
constexpr int TILE_F = ROWS * C;     // 6400 floats = 25.6 KB
constexpr int NBLK   = 512;          // 8192 tiles / 512 = exactly 16 per block

typedef const __attribute__((address_space(1))) void* gp_t;
typedef __attribute__((address_space(3))) void* lp_t;

__device__ __forceinline__ void load16_lds(const float* g, float* l) {
  // 16B per lane, LDS dest = wave-uniform base + lane*16 (lane-linear idiom)
  // aux=2 -> NT (non-temporal) cache policy: x is read exactly once
  __builtin_amdgcn_global_load_lds((gp_t)g, (lp_t)l, 16, 0, 2);
}

// Metric term via BACKWARD scan: last_neg = max pair index with la!=lb.
// P(differ)=24/25 per pair -> last_neg is almost surely in the last few
// pairs; expected work is one 256-pair chunk + a <=few-pair tail.
// Writes out[0] = 0.005 * relu(1 + tail - norm_last).  (k_ce adds CE on top.)
__global__ __launch_bounds__(256)
void k_metric(const float* __restrict__ x, const int* __restrict__ labels,
              const float* __restrict__ M, int P, float* __restrict__ out) {
  __shared__ float  colsq[C];
  __shared__ int    sln[4];
  __shared__ double tred[4];

  const int t = threadIdx.x, lane = t & 63, wid = t >> 6;

  if (t < C) {
    float s = 0.f;
    for (int r = 0; r < C; ++r) {
      float m = M[r * C + t];
      s += m * m;
    }
    colsq[t] = s;
  }

  // ---- backward chunk scan for last_neg (uniform loop, expected 1 iter)
  int last_neg = -1;
  for (long cs = (long)P - 256;; cs -= 256) {
    int p = (int)cs + t;
    int best = -1;
    if (p >= 0 && p < P) {
      int2 l = reinterpret_cast<const int2*>(labels)[p];
      if (l.x != l.y) best = p;
    }
#pragma unroll
    for (int off = 32; off; off >>= 1)
      best = max(best, __shfl_down(best, off, 64));
    if (lane == 0) sln[wid] = best;
    __syncthreads();
    const int bmax = max(max(sln[0], sln[1]), max(sln[2], sln[3]));
    if (bmax >= 0 || cs <= 0) { last_neg = bmax; break; }
    __syncthreads();  // protect sln reuse next iteration
  }

  // ---- tail: all pairs after last_neg are same-label by construction
  double tail = 0.0;
  for (int p = last_neg + 1 + t; p < P; p += 256) {
    const float* e = x + (size_t)p * (2 * C);
    float s = 0.f;
#pragma unroll
    for (int c = 0; c < C; ++c) {
      float d = e[c] - e[C + c];
      s = fmaf(d * d, colsq[c], s);
    }
    tail += (double)sqrtf(s);
  }
#pragma unroll
  for (int off = 32; off; off >>= 1) tail += __shfl_down(tail, off, 64);
  if (lane == 0) tred[wid] = tail;
  __syncthreads();

  if (t == 0) {
    float norm_last = 0.f;
    if (last_neg >= 0) {
      const float* e = x + (size_t)last_neg * (2 * C);
      float s = 0.f;
#pragma unroll
      for (int c = 0; c < C; ++c) {
        float d = e[c] - e[C + c];
        s = fmaf(d * d, colsq[c], s);
      }
      norm_last = sqrtf(s);
    }
    const double tl = (tred[0] + tred[1]) + (tred[2] + tred[3]);
    const float  ml = fmaxf(1.0f + (float)tl - norm_last, 0.0f);
    out[0] = 0.005f * ml;  // fresh base each call (k_ce accumulates CE on top)
  }
}

// CE pass: double-buffered NT async LDS staging; contiguous tile chunk per
// block; one float atomicAdd(out) per block (order noise ~1e-4 << threshold).
__global__ __launch_bounds__(256)
void k_ce(const float* __restrict__ x, const int* __restrict__ labels, int B,
          float invB, float* __restrict__ out) {
  __shared__ float tile[2][TILE_F];  // 51.2 KB double buffer
  __shared__ float wsum[4];

  const int t      = threadIdx.x;
  const int ntiles = B / ROWS;
  const int tpb    = ntiles / NBLK;            // 16 (exact for this problem)
  const int ti0    = blockIdx.x * tpb;
  const int ti1    = min(ti0 + tpb, ntiles);

  float ce_local = 0.f;
  int   cur      = 0;

  // ---- prologue: stage first tile, prefetch its labels
  int lab = 0;
  if (ti0 < ti1) {
    const float* g = x + (size_t)ti0 * TILE_F;
#pragma unroll
    for (int k = 0; k < 6; ++k)
      load16_lds(g + (k * 256 + t) * 4, &tile[0][(k * 256 + t) * 4]);
    if (t < 64) load16_lds(g + (1536 + t) * 4, &tile[0][(1536 + t) * 4]);
    lab = labels[(size_t)ti0 * ROWS + t];
  }

  for (int ti = ti0; ti < ti1; ++ti) {
    __syncthreads();  // drains vmcnt(0): tile[cur] staged & visible block-wide

    const int tnext = ti + 1;
    int labn = 0;
    if (tnext < ti1) {
      const float* g = x + (size_t)tnext * TILE_F;
      float* buf = tile[cur ^ 1];
#pragma unroll
      for (int k = 0; k < 6; ++k)
        load16_lds(g + (k * 256 + t) * 4, &buf[(k * 256 + t) * 4]);
      if (t < 64) load16_lds(g + (1536 + t) * 4, &buf[(1536 + t) * 4]);
      labn = labels[(size_t)tnext * ROWS + t];  // prefetch under compute
    }

    // ---- compute row t of tile[cur]; stride-25-dword LDS reads (2-way = free)
    const float* r = &tile[cur][t * C];
    float e[C];
#pragma unroll
    for (int c = 0; c < C; ++c) e[c] = r[c];

    float m = e[0];
#pragma unroll
    for (int c = 1; c < C; ++c) m = fmaxf(m, e[c]);
    float s = 0.f, xl = 0.f;
#pragma unroll
    for (int c = 0; c < C; ++c) {
      s += __expf(e[c] - m);
      xl = (c == lab) ? e[c] : xl;  // static-index in-register select
    }
    ce_local += (m + __logf(s)) - xl;

    lab = labn;
    cur ^= 1;
  }

  // ---- block reduce, one atomic per block directly into out
#pragma unroll
  for (int off = 32; off; off >>= 1)
    ce_local += __shfl_down(ce_local, off, 64);
  const int lane = t & 63, wid = t >> 6;
  if (lane == 0) wsum[wid] = ce_local;
  __syncthreads();
  if (t == 0) {
    const float bs = (wsum[0] + wsum[1]) + (wsum[2] + wsum[3]);
    atomicAdd(out, bs * invB);
  }
}

}  // namespace

extern "C" void kernel_launch(void* const* d_in, const int* in_sizes, int n_in,
                              void* d_out, int out_size, void* d_ws,
                              size_t ws_size, hipStream_t stream) {
  const float* x      = (const float*)d_in[0];
  const int*   labels = (const int*)d_in[1];
  const float* M      = (const float*)d_in[2];
  float*       out    = (float*)d_out;

  const int B = in_sizes[1];
  const int P = B / 2;

  k_metric<<<1, 256, 0, stream>>>(x, labels, M, P, out);
  k_ce<<<NBLK, 256, 0, stream>>>(x, labels, B, 1.0f / (float)B, out);
}

// Round 13
// 39.702 us; speedup vs baseline: 1.1027x; 1.1027x over previous
//
#include <hip/hip_runtime.h>
#include <math.h>

namespace {

constexpr int C      = 25;
constexpr int ROWS   = 256;          // rows per tile (= blockDim.x)
constexpr int TILE_F = ROWS * C;     // 6400 floats = 25.6 KB
constexpr int NBLK   = 512;          // 8192 tiles / 512 = exactly 16 per block

typedef const __attribute__((address_space(1))) void* gp_t;
typedef __attribute__((address_space(3))) void* lp_t;

__device__ __forceinline__ void load16_lds(const float* g, float* l) {
  // 16B per lane, LDS dest = wave-uniform base + lane*16 (lane-linear idiom)
  // aux=2 -> NT (non-temporal) cache policy: x is read exactly once
  __builtin_amdgcn_global_load_lds((gp_t)g, (lp_t)l, 16, 0, 2);
}

// Fused CE + last_neg pass. Double-buffered NT async LDS staging; each block
// owns a CONTIGUOUS chunk of tiles (sequential HBM stream).
__global__ __launch_bounds__(256)
void k_ce(const float* __restrict__ x, const int* __restrict__ labels, int B,
          double* __restrict__ ce_part, int* __restrict__ ln_part) {
  __shared__ float tile[2][TILE_F];  // 51.2 KB double buffer
  __shared__ float wsum[4];
  __shared__ int   wmax[4];

  const int t      = threadIdx.x;
  const int ntiles = B / ROWS;
  const int tpb    = ntiles / NBLK;            // 16 (exact for this problem)
  const int ti0    = blockIdx.x * tpb;
  const int ti1    = min(ti0 + tpb, ntiles);

  float ce_local = 0.f;
  int   best     = -1;
  int   cur      = 0;

  // ---- prologue: stage first tile, prefetch its labels
  int lab = 0;
  if (ti0 < ti1) {
    const float* g = x + (size_t)ti0 * TILE_F;
#pragma unroll
    for (int k = 0; k < 6; ++k)
      load16_lds(g + (k * 256 + t) * 4, &tile[0][(k * 256 + t) * 4]);
    if (t < 64) load16_lds(g + (1536 + t) * 4, &tile[0][(1536 + t) * 4]);
    lab = labels[(size_t)ti0 * ROWS + t];
  }

  for (int ti = ti0; ti < ti1; ++ti) {
    __syncthreads();  // drains vmcnt(0): tile[cur] staged & visible block-wide

    const int tnext = ti + 1;
    int labn = 0;
    if (tnext < ti1) {
      const float* g = x + (size_t)tnext * TILE_F;
      float* buf = tile[cur ^ 1];
#pragma unroll
      for (int k = 0; k < 6; ++k)
        load16_lds(g + (k * 256 + t) * 4, &buf[(k * 256 + t) * 4]);
      if (t < 64) load16_lds(g + (1536 + t) * 4, &buf[(1536 + t) * 4]);
      labn = labels[(size_t)tnext * ROWS + t];  // prefetch under compute
    }

    // ---- compute row t of tile[cur]; stride-25-dword LDS reads (2-way = free)
    const float* r = &tile[cur][t * C];
    float e[C];
#pragma unroll
    for (int c = 0; c < C; ++c) e[c] = r[c];

    float m = e[0];
#pragma unroll
    for (int c = 1; c < C; ++c) m = fmaxf(m, e[c]);
    float s = 0.f, xl = 0.f;
#pragma unroll
    for (int c = 0; c < C; ++c) {
      s += __expf(e[c] - m);
      xl = (c == lab) ? e[c] : xl;  // static-index in-register select
    }
    ce_local += (m + __logf(s)) - xl;

    // pairs are (even t, t+1): never straddle a wave
    const int nxt = __shfl_down(lab, 1, 64);
    if (((t & 1) == 0) && lab != nxt) best = ((ti * ROWS) + t) >> 1;

    lab = labn;
    cur ^= 1;
  }

  // ---- deterministic per-block partials
#pragma unroll
  for (int off = 32; off; off >>= 1) {
    ce_local += __shfl_down(ce_local, off, 64);
    best = max(best, __shfl_down(best, off, 64));
  }
  const int lane = t & 63, wid = t >> 6;
  if (lane == 0) { wsum[wid] = ce_local; wmax[wid] = best; }
  __syncthreads();
  if (t == 0) {
    ce_part[blockIdx.x] = (double)((wsum[0] + wsum[1]) + (wsum[2] + wsum[3]));
    ln_part[blockIdx.x] = max(max(wmax[0], wmax[1]), max(wmax[2], wmax[3]));
  }
}

// Finalize: reduce partials; metric tail (suffix past last_neg is all
// same-label by construction) + norm at last_neg; combine. One block.
__global__ __launch_bounds__(256)
void k_fin(const float* __restrict__ x, const float* __restrict__ M,
           const double* __restrict__ ce_part, const int* __restrict__ ln_part,
           int P, int B, float* __restrict__ out) {
  __shared__ float  colsq[C];
  __shared__ double sred[4];
  __shared__ int    ired[4];
  __shared__ double tred[4];
  __shared__ int    s_last;

  const int t = threadIdx.x, lane = t & 63, wid = t >> 6;

  if (t < C) {
    float s = 0.f;
    for (int r = 0; r < C; ++r) {
      float m = M[r * C + t];
      s += m * m;
    }
    colsq[t] = s;
  }

  double ce = 0.0;
  int ln = -1;
  for (int i = t; i < NBLK; i += 256) {
    ce += ce_part[i];
    ln = max(ln, ln_part[i]);
  }
#pragma unroll
  for (int off = 32; off; off >>= 1) {
    ce += __shfl_down(ce, off, 64);
    ln = max(ln, __shfl_down(ln, off, 64));
  }
  if (lane == 0) { sred[wid] = ce; ired[wid] = ln; }
  __syncthreads();
  if (t == 0) s_last = max(max(ired[0], ired[1]), max(ired[2], ired[3]));
  __syncthreads();
  const int last_neg = s_last;

  double tail = 0.0;
  for (int p = last_neg + 1 + t; p < P; p += 256) {
    const float* e = x + (size_t)p * (2 * C);
    float s = 0.f;
#pragma unroll
    for (int c = 0; c < C; ++c) {
      float d = e[c] - e[C + c];
      s = fmaf(d * d, colsq[c], s);
    }
    tail += (double)sqrtf(s);
  }
  float norm_last = 0.f;
  if (t == 0 && last_neg >= 0) {
    const float* e = x + (size_t)last_neg * (2 * C);
    float s = 0.f;
#pragma unroll
    for (int c = 0; c < C; ++c) {
      float d = e[c] - e[C + c];
      s = fmaf(d * d, colsq[c], s);
    }
    norm_last = sqrtf(s);
  }
#pragma unroll
  for (int off = 32; off; off >>= 1) tail += __shfl_down(tail, off, 64);
  if (lane == 0) tred[wid] = tail;
  __syncthreads();
  if (t == 0) {
    double tl    = (tred[0] + tred[1]) + (tred[2] + tred[3]);
    double cesum = (sred[0] + sred[1]) + (sred[2] + sred[3]);
    double cem   = cesum / (double)B;
    float  ml    = fmaxf(1.0f + (float)tl - norm_last, 0.0f);
    out[0] = (float)(cem + 0.005 * (double)ml);
  }
}

}  // namespace

extern "C" void kernel_launch(void* const* d_in, const int* in_sizes, int n_in,
                              void* d_out, int out_size, void* d_ws,
                              size_t ws_size, hipStream_t stream) {
  const float* x      = (const float*)d_in[0];
  const int*   labels = (const int*)d_in[1];
  const float* M      = (const float*)d_in[2];
  float*       out    = (float*)d_out;

  double* ce_part = (double*)d_ws;
  int*    ln_part = (int*)((char*)d_ws + NBLK * sizeof(double));

  const int B = in_sizes[1];
  const int P = B / 2;

  k_ce<<<NBLK, 256, 0, stream>>>(x, labels, B, ce_part, ln_part);
  k_fin<<<1, 256, 0, stream>>>(x, M, ce_part, ln_part, P, B, out);
}